// Round 1
// baseline (1932.013 us; speedup 1.0000x reference)
//
#include <hip/hip_runtime.h>

constexpr int ED = 64;    // edge feature dim
constexpr int ND = 128;   // node feature dim

// One wave (64 lanes) per edge. Lane j computes output cols j and j+64.
// W columns live in VGPRs (loaded once per wave); the per-edge activation
// row is broadcast lane-by-lane with v_readlane -> SGPR operand into v_fma.
__global__ __launch_bounds__(256, 2)
void edge_scatter_kernel(const float* __restrict__ x,
                         const float* __restrict__ W,
                         const float* __restrict__ bias,
                         const float* __restrict__ gamma,
                         const float* __restrict__ beta,
                         const int*   __restrict__ ei,
                         int E,
                         float* __restrict__ out,
                         float* __restrict__ deg)
{
    const int lane = threadIdx.x & 63;
    const int wid  = (blockIdx.x * (blockDim.x >> 6)) + (threadIdx.x >> 6);
    const int nw   = gridDim.x * (blockDim.x >> 6);

    // Per-lane W columns: w0[k] = W[k][lane], w1[k] = W[k][lane+64]
    float w0[ED], w1[ED];
#pragma unroll
    for (int k = 0; k < ED; ++k) {
        w0[k] = W[k * ND + lane];
        w1[k] = W[k * ND + lane + 64];
    }
    const float b0 = bias[lane],  b1 = bias[lane + 64];
    const float g0 = gamma[lane], g1 = gamma[lane + 64];
    const float p0 = beta[lane],  p1 = beta[lane + 64];

    for (int e = wid; e < E; e += nw) {
        // coalesced 256B row load: lane k holds x[e][k]
        const float xv = x[(size_t)e * ED + lane];
        const int   xi = __float_as_int(xv);

        float h0 = b0, h1 = b1;
#pragma unroll
        for (int k = 0; k < ED; ++k) {
            const float xk = __int_as_float(__builtin_amdgcn_readlane(xi, k));
            h0 = fmaf(xk, w0[k], h0);
            h1 = fmaf(xk, w1[k], h1);
        }
        // ReLU
        h0 = fmaxf(h0, 0.0f);
        h1 = fmaxf(h1, 0.0f);

        // LayerNorm over 128 values (2 per lane): wave-wide sum / sumsq
        float s  = h0 + h1;
        float s2 = fmaf(h0, h0, h1 * h1);
#pragma unroll
        for (int m = 1; m < 64; m <<= 1) {
            s  += __shfl_xor(s,  m, 64);
            s2 += __shfl_xor(s2, m, 64);
        }
        const float mu  = s * (1.0f / ND);
        const float var = s2 * (1.0f / ND) - mu * mu;
        const float rs  = rsqrtf(var + 1e-5f);
        const float y0  = (h0 - mu) * rs * g0 + p0;
        const float y1  = (h1 - mu) * rs * g1 + p1;

        const int sn = ei[e];       // src
        const int dn = ei[E + e];   // dst

        // dual-endpoint scatter-add (coalesced 64-lane atomic instructions)
        unsafeAtomicAdd(&out[(size_t)dn * ND + lane],      y0);
        unsafeAtomicAdd(&out[(size_t)dn * ND + lane + 64], y1);
        unsafeAtomicAdd(&out[(size_t)sn * ND + lane],      y0);
        unsafeAtomicAdd(&out[(size_t)sn * ND + lane + 64], y1);

        if (lane == 0) unsafeAtomicAdd(&deg[dn], 1.0f);
        if (lane == 1) unsafeAtomicAdd(&deg[sn], 1.0f);
    }
}

__global__ void finalize_kernel(float* __restrict__ out,
                                const float* __restrict__ deg,
                                int total)
{
    const int i = blockIdx.x * blockDim.x + threadIdx.x;
    if (i < total) {
        const float d = fmaxf(deg[i >> 7], 1.0f);
        out[i] = out[i] / d;
    }
}

extern "C" void kernel_launch(void* const* d_in, const int* in_sizes, int n_in,
                              void* d_out, int out_size, void* d_ws, size_t ws_size,
                              hipStream_t stream)
{
    const float* x     = (const float*)d_in[0];
    const float* W     = (const float*)d_in[1];
    const float* bias  = (const float*)d_in[2];
    const float* gamma = (const float*)d_in[3];
    const float* beta  = (const float*)d_in[4];
    const int*   ei    = (const int*)d_in[5];
    // d_in[6] = num_nodes scalar on device; host-side value from out_size.

    const int E       = in_sizes[0] / ED;
    const int n_nodes = out_size / ND;

    float* out = (float*)d_out;
    float* deg = (float*)d_ws;

    // zero accumulators (harness re-poisons d_out/d_ws to 0xAA every call)
    hipMemsetAsync(d_out, 0, (size_t)out_size * sizeof(float), stream);
    hipMemsetAsync(d_ws,  0, (size_t)n_nodes * sizeof(float), stream);

    edge_scatter_kernel<<<4096, 256, 0, stream>>>(x, W, bias, gamma, beta,
                                                  ei, E, out, deg);

    finalize_kernel<<<(out_size + 255) / 256, 256, 0, stream>>>(out, deg, out_size);
}